// Round 1
// baseline (147.033 us; speedup 1.0000x reference)
//
#include <hip/hip_runtime.h>
#include <hip/hip_bf16.h>

typedef __bf16 bf16;
typedef __attribute__((ext_vector_type(4))) __bf16 bf16x4;
typedef __attribute__((ext_vector_type(8))) __bf16 bf16x8;
typedef __attribute__((ext_vector_type(4))) float f32x4;

#define D_MODEL 1024
#define DK 128
#define LSEQ 2048
#define SCALE 0.08838834764831845f   // 1/sqrt(128)
#define LOG2E 1.4426950408889634f

// ---------------------------------------------------------------------------
// Kernel 0: transpose + bf16-convert weights. W[1024][128] f32 -> Wt[3][128][1024] bf16
// ---------------------------------------------------------------------------
__global__ __launch_bounds__(256) void wt_kernel(
    const float* __restrict__ Wq, const float* __restrict__ Wk,
    const float* __restrict__ Wv, bf16* __restrict__ Wt)
{
    __shared__ bf16 tile[64][72];
    const float* W = (blockIdx.z == 0) ? Wq : (blockIdx.z == 1) ? Wk : Wv;
    int k0 = blockIdx.x * 64;
    int n0 = blockIdx.y * 64;
    int t  = threadIdx.x;
    #pragma unroll
    for (int i = 0; i < 16; ++i) {
        int idx = t + i * 256;
        int r = idx >> 6, c = idx & 63;          // r: k-row, c: n-col
        tile[c][r] = (bf16)W[(size_t)(k0 + r) * DK + n0 + c];
    }
    __syncthreads();
    bf16* out = Wt + (size_t)blockIdx.z * DK * D_MODEL;
    #pragma unroll
    for (int i = 0; i < 16; ++i) {
        int idx = t + i * 256;
        int rr = idx >> 6, cc = idx & 63;        // rr: n-row, cc: k-col
        out[(size_t)(n0 + rr) * D_MODEL + k0 + cc] = tile[rr][cc];
    }
}

// ---------------------------------------------------------------------------
// Kernel 1: QKV projection GEMM (bf16 MFMA).
// X[8192][1024] f32, Wt[mat][128][1024] bf16 ->
//   mat0: Qs[8192][128] bf16 (pre-scaled by 1/sqrt(dk))
//   mat1: Kb[8192][128] bf16
//   mat2: Vt[b][128][2048] bf16 (V transposed per batch)
// Block: 256 thr, M-tile 128, 4 waves x 32 rows, BK=64.
// ---------------------------------------------------------------------------
__global__ __launch_bounds__(256) void proj_kernel(
    const float* __restrict__ X, const bf16* __restrict__ Wt,
    bf16* __restrict__ Qs, bf16* __restrict__ Kb, bf16* __restrict__ Vt)
{
    __shared__ bf16 Xs[128][72];   // +8 pad: 2-way banks only
    __shared__ bf16 Ws[128][72];
    int mt = blockIdx.x, mat = blockIdx.y;
    const bf16* W = Wt + (size_t)mat * DK * D_MODEL;
    int t = threadIdx.x;
    int wave = t >> 6, lane = t & 63;
    int lq = lane & 15, g = lane >> 4;
    int row0 = mt * 128;

    f32x4 acc[2][8];
    #pragma unroll
    for (int m = 0; m < 2; ++m)
        #pragma unroll
        for (int n = 0; n < 8; ++n) acc[m][n] = f32x4{0.f, 0.f, 0.f, 0.f};

    for (int k0 = 0; k0 < D_MODEL; k0 += 64) {
        __syncthreads();
        // stage X tile 128x64 f32 -> bf16
        #pragma unroll
        for (int i = 0; i < 8; ++i) {
            int idx = t + i * 256;                // float4 slots
            int r = idx >> 4, c4 = idx & 15;
            f32x4 v = *reinterpret_cast<const f32x4*>(
                &X[(size_t)(row0 + r) * D_MODEL + k0 + c4 * 4]);
            bf16x4 h; h[0]=(bf16)v[0]; h[1]=(bf16)v[1]; h[2]=(bf16)v[2]; h[3]=(bf16)v[3];
            *reinterpret_cast<bf16x4*>(&Xs[r][c4 * 4]) = h;
        }
        // stage Wt tile 128x64 bf16
        #pragma unroll
        for (int i = 0; i < 4; ++i) {
            int idx = t + i * 256;                // 16B chunks
            int r = idx >> 3, c8 = idx & 7;
            *reinterpret_cast<bf16x8*>(&Ws[r][c8 * 8]) =
                *reinterpret_cast<const bf16x8*>(&W[(size_t)r * D_MODEL + k0 + c8 * 8]);
        }
        __syncthreads();
        #pragma unroll
        for (int kk = 0; kk < 2; ++kk) {
            bf16x8 a0 = *reinterpret_cast<const bf16x8*>(&Xs[wave * 32 +      lq][kk * 32 + g * 8]);
            bf16x8 a1 = *reinterpret_cast<const bf16x8*>(&Xs[wave * 32 + 16 + lq][kk * 32 + g * 8]);
            #pragma unroll
            for (int nt = 0; nt < 8; ++nt) {
                bf16x8 bfr = *reinterpret_cast<const bf16x8*>(&Ws[nt * 16 + lq][kk * 32 + g * 8]);
                acc[0][nt] = __builtin_amdgcn_mfma_f32_16x16x32_bf16(a0, bfr, acc[0][nt], 0, 0, 0);
                acc[1][nt] = __builtin_amdgcn_mfma_f32_16x16x32_bf16(a1, bfr, acc[1][nt], 0, 0, 0);
            }
        }
    }
    // epilogue: D layout col = lane&15 (n), row = (lane>>4)*4 + r (m)
    #pragma unroll
    for (int m = 0; m < 2; ++m) {
        int rbase = row0 + wave * 32 + m * 16 + g * 4;
        if (mat == 0) {
            #pragma unroll
            for (int nt = 0; nt < 8; ++nt)
                #pragma unroll
                for (int r = 0; r < 4; ++r)
                    Qs[(size_t)(rbase + r) * DK + nt * 16 + lq] = (bf16)(acc[m][nt][r] * SCALE);
        } else if (mat == 1) {
            #pragma unroll
            for (int nt = 0; nt < 8; ++nt)
                #pragma unroll
                for (int r = 0; r < 4; ++r)
                    Kb[(size_t)(rbase + r) * DK + nt * 16 + lq] = (bf16)acc[m][nt][r];
        } else {
            int bb  = rbase >> 11;       // row / 2048
            int kv0 = rbase & 2047;
            #pragma unroll
            for (int nt = 0; nt < 8; ++nt) {
                bf16x4 h;
                h[0]=(bf16)acc[m][nt][0]; h[1]=(bf16)acc[m][nt][1];
                h[2]=(bf16)acc[m][nt][2]; h[3]=(bf16)acc[m][nt][3];
                *reinterpret_cast<bf16x4*>(
                    &Vt[((size_t)bb * DK + nt * 16 + lq) * LSEQ + kv0]) = h;
            }
        }
    }
}

// ---------------------------------------------------------------------------
// Kernel 2: causal flash attention. One wave (64 thr) per 16 q-rows.
// S^T = mfma(K, Q): lane col = q -> softmax is in-lane + 2 shfl_xor.
// Z^T = mfma(V^T, P^T) with P re-fragmented through LDS.
// ---------------------------------------------------------------------------
__global__ __launch_bounds__(64) void attn_kernel(
    const bf16* __restrict__ Qs, const bf16* __restrict__ Kb,
    const bf16* __restrict__ Vt, float* __restrict__ Out)
{
    __shared__ bf16 P[16][40];    // [q][kv] padded (+8)
    int b  = blockIdx.y;
    int q0 = blockIdx.x * 16;
    int lane = threadIdx.x;
    int lq = lane & 15, g = lane >> 4;
    int qg = q0 + lq;             // this lane's q row (fragment column)

    const bf16* Qrow = Qs + ((size_t)b * LSEQ + qg) * DK;
    bf16x8 qf[4];
    #pragma unroll
    for (int ks = 0; ks < 4; ++ks)
        qf[ks] = *reinterpret_cast<const bf16x8*>(&Qrow[ks * 32 + g * 8]);

    f32x4 z[8];
    #pragma unroll
    for (int i = 0; i < 8; ++i) z[i] = f32x4{0.f, 0.f, 0.f, 0.f};
    float mrun = -3.0e38f, lrun = 0.f;

    const bf16* Kbase = Kb + (size_t)b * LSEQ * DK;
    const bf16* Vbase = Vt + (size_t)b * DK * LSEQ;

    int ntile = ((q0 + 15) >> 5) + 1;
    for (int ti = 0; ti < ntile; ++ti) {
        int kvb = ti * 32;
        f32x4 s0 = {0.f,0.f,0.f,0.f}, s1 = {0.f,0.f,0.f,0.f};
        const bf16* K0 = Kbase + (size_t)(kvb + lq) * DK;
        const bf16* K1 = K0 + 16 * DK;
        #pragma unroll
        for (int ks = 0; ks < 4; ++ks) {
            bf16x8 a0 = *reinterpret_cast<const bf16x8*>(&K0[ks * 32 + g * 8]);
            bf16x8 a1 = *reinterpret_cast<const bf16x8*>(&K1[ks * 32 + g * 8]);
            s0 = __builtin_amdgcn_mfma_f32_16x16x32_bf16(a0, qf[ks], s0, 0, 0, 0);
            s1 = __builtin_amdgcn_mfma_f32_16x16x32_bf16(a1, qf[ks], s1, 0, 0, 0);
        }
        // causal mask + tile max; element (half,r): kv = kvb + half*16 + g*4 + r
        float sv[8]; float mt = -3.0e38f;
        #pragma unroll
        for (int r = 0; r < 4; ++r) {
            int kv0 = kvb + g * 4 + r;
            sv[r]     = (kv0      <= qg) ? s0[r] : -3.0e38f;
            sv[4 + r] = (kv0 + 16 <= qg) ? s1[r] : -3.0e38f;
            mt = fmaxf(mt, fmaxf(sv[r], sv[4 + r]));
        }
        mt = fmaxf(mt, __shfl_xor(mt, 16));
        mt = fmaxf(mt, __shfl_xor(mt, 32));
        float mnew  = fmaxf(mrun, mt);
        float alpha = exp2f((mrun - mnew) * LOG2E);
        float psum = 0.f;
        bf16x4 p0, p1;
        #pragma unroll
        for (int r = 0; r < 4; ++r) {
            float e0 = exp2f((sv[r]     - mnew) * LOG2E);
            float e1 = exp2f((sv[4 + r] - mnew) * LOG2E);
            psum += e0 + e1;
            p0[r] = (bf16)e0; p1[r] = (bf16)e1;
        }
        psum += __shfl_xor(psum, 16);
        psum += __shfl_xor(psum, 32);
        lrun = lrun * alpha + psum;
        mrun = mnew;
        #pragma unroll
        for (int i = 0; i < 8; ++i) {
            z[i][0] *= alpha; z[i][1] *= alpha; z[i][2] *= alpha; z[i][3] *= alpha;
        }
        __syncthreads();
        *reinterpret_cast<bf16x4*>(&P[lq][     g * 4]) = p0;
        *reinterpret_cast<bf16x4*>(&P[lq][16 + g * 4]) = p1;
        __syncthreads();
        bf16x8 pf = *reinterpret_cast<const bf16x8*>(&P[lq][g * 8]);
        #pragma unroll
        for (int dt = 0; dt < 8; ++dt) {
            const bf16* Vrow = Vbase + (size_t)(dt * 16 + lq) * LSEQ + kvb;
            bf16x8 av = *reinterpret_cast<const bf16x8*>(&Vrow[g * 8]);
            z[dt] = __builtin_amdgcn_mfma_f32_16x16x32_bf16(av, pf, z[dt], 0, 0, 0);
        }
    }
    float inv = 1.f / lrun;
    float* orow = Out + ((size_t)b * LSEQ + qg) * DK;
    #pragma unroll
    for (int dt = 0; dt < 8; ++dt) {
        f32x4 v;
        v[0]=z[dt][0]*inv; v[1]=z[dt][1]*inv; v[2]=z[dt][2]*inv; v[3]=z[dt][3]*inv;
        *reinterpret_cast<f32x4*>(&orow[dt * 16 + g * 4]) = v;
    }
}

// ---------------------------------------------------------------------------
extern "C" void kernel_launch(void* const* d_in, const int* in_sizes, int n_in,
                              void* d_out, int out_size, void* d_ws, size_t ws_size,
                              hipStream_t stream)
{
    const float* X  = (const float*)d_in[0];
    const float* Wq = (const float*)d_in[1];
    const float* Wk = (const float*)d_in[2];
    const float* Wv = (const float*)d_in[3];
    float* Out = (float*)d_out;

    char* ws = (char*)d_ws;
    // layout: Wt 768KB @0 ; Qs 2MB @1MB ; Kb 2MB @3MB ; Vt 2MB @5MB  (total 7MB)
    bf16* Wt = (bf16*)(ws);
    bf16* Qs = (bf16*)(ws + (size_t)1 * (1 << 20));
    bf16* Kb = (bf16*)(ws + (size_t)3 * (1 << 20));
    bf16* Vt = (bf16*)(ws + (size_t)5 * (1 << 20));

    hipLaunchKernelGGL(wt_kernel,   dim3(16, 2, 3), dim3(256), 0, stream, Wq, Wk, Wv, Wt);
    hipLaunchKernelGGL(proj_kernel, dim3(64, 3),    dim3(256), 0, stream, X, Wt, Qs, Kb, Vt);
    hipLaunchKernelGGL(attn_kernel, dim3(128, 4),   dim3(64),  0, stream, Qs, Kb, Vt, Out);
}

// Round 2
// 93.528 us; speedup vs baseline: 1.5721x; 1.5721x over previous
//
#include <hip/hip_runtime.h>
#include <hip/hip_bf16.h>

typedef __bf16 bf16;
typedef __attribute__((ext_vector_type(4))) __bf16 bf16x4;
typedef __attribute__((ext_vector_type(8))) __bf16 bf16x8;
typedef __attribute__((ext_vector_type(4))) float f32x4;

#define D_MODEL 1024
#define DK 128
#define LSEQ 2048
#define NQT 128                       // q-tiles (16 rows) per batch
#define NB 4
// 1/sqrt(128) * log2(e): softmax runs in exp2 domain end-to-end
#define SCALE2 (0.08838834764831845f * 1.4426950408889634f)

// ---------------------------------------------------------------------------
// Kernel 0: transpose + bf16-convert weights. W[1024][128] f32 -> Wt[3][128][1024] bf16
// ---------------------------------------------------------------------------
__global__ __launch_bounds__(256) void wt_kernel(
    const float* __restrict__ Wq, const float* __restrict__ Wk,
    const float* __restrict__ Wv, bf16* __restrict__ Wt)
{
    __shared__ bf16 tile[64][72];
    const float* W = (blockIdx.z == 0) ? Wq : (blockIdx.z == 1) ? Wk : Wv;
    int k0 = blockIdx.x * 64;
    int n0 = blockIdx.y * 64;
    int t  = threadIdx.x;
    #pragma unroll
    for (int i = 0; i < 16; ++i) {
        int idx = t + i * 256;
        int r = idx >> 6, c = idx & 63;
        tile[c][r] = (bf16)W[(size_t)(k0 + r) * DK + n0 + c];
    }
    __syncthreads();
    bf16* out = Wt + (size_t)blockIdx.z * DK * D_MODEL;
    #pragma unroll
    for (int i = 0; i < 16; ++i) {
        int idx = t + i * 256;
        int rr = idx >> 6, cc = idx & 63;
        out[(size_t)(n0 + rr) * D_MODEL + k0 + cc] = tile[rr][cc];
    }
}

// ---------------------------------------------------------------------------
// Kernel 1: QKV projection GEMM (bf16 MFMA). Unchanged from R0 except Q is
// pre-scaled by 1/sqrt(dk)*log2(e) so attention softmax is pure exp2.
// ---------------------------------------------------------------------------
__global__ __launch_bounds__(256) void proj_kernel(
    const float* __restrict__ X, const bf16* __restrict__ Wt,
    bf16* __restrict__ Qs, bf16* __restrict__ Kb, bf16* __restrict__ Vt)
{
    __shared__ bf16 Xs[128][72];
    __shared__ bf16 Ws[128][72];
    int mt = blockIdx.x, mat = blockIdx.y;
    const bf16* W = Wt + (size_t)mat * DK * D_MODEL;
    int t = threadIdx.x;
    int wave = t >> 6, lane = t & 63;
    int lq = lane & 15, g = lane >> 4;
    int row0 = mt * 128;

    f32x4 acc[2][8];
    #pragma unroll
    for (int m = 0; m < 2; ++m)
        #pragma unroll
        for (int n = 0; n < 8; ++n) acc[m][n] = f32x4{0.f, 0.f, 0.f, 0.f};

    for (int k0 = 0; k0 < D_MODEL; k0 += 64) {
        __syncthreads();
        #pragma unroll
        for (int i = 0; i < 8; ++i) {
            int idx = t + i * 256;
            int r = idx >> 4, c4 = idx & 15;
            f32x4 v = *reinterpret_cast<const f32x4*>(
                &X[(size_t)(row0 + r) * D_MODEL + k0 + c4 * 4]);
            bf16x4 h; h[0]=(bf16)v[0]; h[1]=(bf16)v[1]; h[2]=(bf16)v[2]; h[3]=(bf16)v[3];
            *reinterpret_cast<bf16x4*>(&Xs[r][c4 * 4]) = h;
        }
        #pragma unroll
        for (int i = 0; i < 4; ++i) {
            int idx = t + i * 256;
            int r = idx >> 3, c8 = idx & 7;
            *reinterpret_cast<bf16x8*>(&Ws[r][c8 * 8]) =
                *reinterpret_cast<const bf16x8*>(&W[(size_t)r * D_MODEL + k0 + c8 * 8]);
        }
        __syncthreads();
        #pragma unroll
        for (int kk = 0; kk < 2; ++kk) {
            bf16x8 a0 = *reinterpret_cast<const bf16x8*>(&Xs[wave * 32 +      lq][kk * 32 + g * 8]);
            bf16x8 a1 = *reinterpret_cast<const bf16x8*>(&Xs[wave * 32 + 16 + lq][kk * 32 + g * 8]);
            #pragma unroll
            for (int nt = 0; nt < 8; ++nt) {
                bf16x8 bfr = *reinterpret_cast<const bf16x8*>(&Ws[nt * 16 + lq][kk * 32 + g * 8]);
                acc[0][nt] = __builtin_amdgcn_mfma_f32_16x16x32_bf16(a0, bfr, acc[0][nt], 0, 0, 0);
                acc[1][nt] = __builtin_amdgcn_mfma_f32_16x16x32_bf16(a1, bfr, acc[1][nt], 0, 0, 0);
            }
        }
    }
    #pragma unroll
    for (int m = 0; m < 2; ++m) {
        int rbase = row0 + wave * 32 + m * 16 + g * 4;
        if (mat == 0) {
            #pragma unroll
            for (int nt = 0; nt < 8; ++nt)
                #pragma unroll
                for (int r = 0; r < 4; ++r)
                    Qs[(size_t)(rbase + r) * DK + nt * 16 + lq] = (bf16)(acc[m][nt][r] * SCALE2);
        } else if (mat == 1) {
            #pragma unroll
            for (int nt = 0; nt < 8; ++nt)
                #pragma unroll
                for (int r = 0; r < 4; ++r)
                    Kb[(size_t)(rbase + r) * DK + nt * 16 + lq] = (bf16)acc[m][nt][r];
        } else {
            int bb  = rbase >> 11;
            int kv0 = rbase & 2047;
            #pragma unroll
            for (int nt = 0; nt < 8; ++nt) {
                bf16x4 h;
                h[0]=(bf16)acc[m][nt][0]; h[1]=(bf16)acc[m][nt][1];
                h[2]=(bf16)acc[m][nt][2]; h[3]=(bf16)acc[m][nt][3];
                *reinterpret_cast<bf16x4*>(
                    &Vt[((size_t)bb * DK + nt * 16 + lq) * LSEQ + kv0]) = h;
            }
        }
    }
}

// ---------------------------------------------------------------------------
// Kernel 2: split-KV causal flash attention. One wave per (b, q-tile16, chunk).
// Chunk = contiguous range of 32-kv tiles; partial (Z,m,l) written to ws,
// merged by combine_kernel. S==1 && direct: write Out straight.
// Softmax in exp2 domain (Q pre-scaled by log2e). Only the diagonal tile masks.
// ---------------------------------------------------------------------------
__global__ __launch_bounds__(64) void attn_kernel(
    const bf16* __restrict__ Qs, const bf16* __restrict__ Kb,
    const bf16* __restrict__ Vt, float* __restrict__ Zp,
    float* __restrict__ Mp, float* __restrict__ Lp,
    float* __restrict__ Out, int S, int direct)
{
    __shared__ bf16 P[16][40];
    int s  = blockIdx.x;
    int qt = blockIdx.y;
    int b  = blockIdx.z;
    int q0 = qt * 16;
    int lane = threadIdx.x;
    int lq = lane & 15, g = lane >> 4;
    int qg = q0 + lq;

    int nt  = (q0 + 47) >> 5;            // total 32-kv tiles for this q-tile
    int cpt = (nt + S - 1) / S;          // tiles per chunk
    int t0  = s * cpt;
    int t1  = min(t0 + cpt, nt);

    const bf16* Qrow = Qs + ((size_t)b * LSEQ + qg) * DK;
    bf16x8 qf[4];
    #pragma unroll
    for (int ks = 0; ks < 4; ++ks)
        qf[ks] = *reinterpret_cast<const bf16x8*>(&Qrow[ks * 32 + g * 8]);

    f32x4 z[8];
    #pragma unroll
    for (int i = 0; i < 8; ++i) z[i] = f32x4{0.f, 0.f, 0.f, 0.f};
    float mrun = -3.0e38f, lrun = 0.f;

    const bf16* Kbase = Kb + (size_t)b * LSEQ * DK;
    const bf16* Vbase = Vt + (size_t)b * DK * LSEQ;

    for (int ti = t0; ti < t1; ++ti) {
        int kvb = ti * 32;
        f32x4 s0 = {0.f,0.f,0.f,0.f}, s1 = {0.f,0.f,0.f,0.f};
        const bf16* K0 = Kbase + (size_t)(kvb + lq) * DK;
        const bf16* K1 = K0 + 16 * DK;
        #pragma unroll
        for (int ks = 0; ks < 4; ++ks) {
            bf16x8 a0 = *reinterpret_cast<const bf16x8*>(&K0[ks * 32 + g * 8]);
            bf16x8 a1 = *reinterpret_cast<const bf16x8*>(&K1[ks * 32 + g * 8]);
            s0 = __builtin_amdgcn_mfma_f32_16x16x32_bf16(a0, qf[ks], s0, 0, 0, 0);
            s1 = __builtin_amdgcn_mfma_f32_16x16x32_bf16(a1, qf[ks], s1, 0, 0, 0);
        }
        float sv[8];
        if (ti == nt - 1) {              // only the diagonal tile straddles
            #pragma unroll
            for (int r = 0; r < 4; ++r) {
                int kv0 = kvb + g * 4 + r;
                sv[r]     = (kv0      <= qg) ? s0[r] : -3.0e38f;
                sv[4 + r] = (kv0 + 16 <= qg) ? s1[r] : -3.0e38f;
            }
        } else {
            #pragma unroll
            for (int r = 0; r < 4; ++r) { sv[r] = s0[r]; sv[4 + r] = s1[r]; }
        }
        float mt = fmaxf(fmaxf(fmaxf(sv[0], sv[1]), fmaxf(sv[2], sv[3])),
                         fmaxf(fmaxf(sv[4], sv[5]), fmaxf(sv[6], sv[7])));
        mt = fmaxf(mt, __shfl_xor(mt, 16));
        mt = fmaxf(mt, __shfl_xor(mt, 32));
        if (!__all(mt <= mrun)) {        // exact skip: no new max anywhere
            float mnew  = fmaxf(mrun, mt);
            float alpha = exp2f(mrun - mnew);
            lrun *= alpha;
            #pragma unroll
            for (int i = 0; i < 8; ++i) {
                z[i][0] *= alpha; z[i][1] *= alpha; z[i][2] *= alpha; z[i][3] *= alpha;
            }
            mrun = mnew;
        }
        float psum = 0.f;
        bf16x4 p0, p1;
        #pragma unroll
        for (int r = 0; r < 4; ++r) {
            float e0 = exp2f(sv[r]     - mrun);
            float e1 = exp2f(sv[4 + r] - mrun);
            psum += e0 + e1;
            p0[r] = (bf16)e0; p1[r] = (bf16)e1;
        }
        psum += __shfl_xor(psum, 16);
        psum += __shfl_xor(psum, 32);
        lrun += psum;
        __syncthreads();
        *reinterpret_cast<bf16x4*>(&P[lq][     g * 4]) = p0;
        *reinterpret_cast<bf16x4*>(&P[lq][16 + g * 4]) = p1;
        __syncthreads();
        bf16x8 pf = *reinterpret_cast<const bf16x8*>(&P[lq][g * 8]);
        #pragma unroll
        for (int dt = 0; dt < 8; ++dt) {
            const bf16* Vrow = Vbase + (size_t)(dt * 16 + lq) * LSEQ + kvb;
            bf16x8 av = *reinterpret_cast<const bf16x8*>(&Vrow[g * 8]);
            z[dt] = __builtin_amdgcn_mfma_f32_16x16x32_bf16(av, pf, z[dt], 0, 0, 0);
        }
    }

    if (direct) {
        float inv = 1.f / lrun;
        float* orow = Out + ((size_t)b * LSEQ + qg) * DK;
        #pragma unroll
        for (int dt = 0; dt < 8; ++dt) {
            f32x4 v;
            v[0]=z[dt][0]*inv; v[1]=z[dt][1]*inv; v[2]=z[dt][2]*inv; v[3]=z[dt][3]*inv;
            *reinterpret_cast<f32x4*>(&orow[dt * 16 + g * 4]) = v;
        }
    } else {
        size_t T = ((size_t)(b * NQT + qt) * S + s);
        float* zp = Zp + T * (16 * 128);
        #pragma unroll
        for (int dt = 0; dt < 8; ++dt)
            *reinterpret_cast<f32x4*>(&zp[lq * 128 + dt * 16 + g * 4]) = z[dt];
        if (g == 0) {
            Mp[T * 16 + lq] = mrun;
            Lp[T * 16 + lq] = lrun;
        }
    }
}

// ---------------------------------------------------------------------------
// Kernel 3: merge split-KV partials. One block per (qt, b), 256 threads.
// ---------------------------------------------------------------------------
__global__ __launch_bounds__(256) void combine_kernel(
    const float* __restrict__ Zp, const float* __restrict__ Mp,
    const float* __restrict__ Lp, float* __restrict__ Out, int S)
{
    int qt = blockIdx.x, b = blockIdx.y;
    int t  = threadIdx.x;
    int r  = t >> 4;                 // q-row within tile
    int d0 = (t & 15) * 8;           // 8 contiguous d per thread
    size_t Tbase = (size_t)(b * NQT + qt) * S;

    float m = -3.0e38f;
    for (int s = 0; s < S; ++s)
        m = fmaxf(m, Mp[(Tbase + s) * 16 + r]);

    float L = 0.f;
    f32x4 a0 = {0.f,0.f,0.f,0.f}, a1 = {0.f,0.f,0.f,0.f};
    for (int s = 0; s < S; ++s) {
        float w = exp2f(Mp[(Tbase + s) * 16 + r] - m);   // m already log2-domain
        L += w * Lp[(Tbase + s) * 16 + r];
        const float* zp = Zp + (Tbase + s) * (16 * 128) + r * 128 + d0;
        f32x4 v0 = *reinterpret_cast<const f32x4*>(&zp[0]);
        f32x4 v1 = *reinterpret_cast<const f32x4*>(&zp[4]);
        a0[0]+=w*v0[0]; a0[1]+=w*v0[1]; a0[2]+=w*v0[2]; a0[3]+=w*v0[3];
        a1[0]+=w*v1[0]; a1[1]+=w*v1[1]; a1[2]+=w*v1[2]; a1[3]+=w*v1[3];
    }
    float inv = 1.f / L;
    float* orow = Out + ((size_t)b * LSEQ + qt * 16 + r) * DK + d0;
    f32x4 o0, o1;
    o0[0]=a0[0]*inv; o0[1]=a0[1]*inv; o0[2]=a0[2]*inv; o0[3]=a0[3]*inv;
    o1[0]=a1[0]*inv; o1[1]=a1[1]*inv; o1[2]=a1[2]*inv; o1[3]=a1[3]*inv;
    *reinterpret_cast<f32x4*>(&orow[0]) = o0;
    *reinterpret_cast<f32x4*>(&orow[4]) = o1;
}

// ---------------------------------------------------------------------------
extern "C" void kernel_launch(void* const* d_in, const int* in_sizes, int n_in,
                              void* d_out, int out_size, void* d_ws, size_t ws_size,
                              hipStream_t stream)
{
    const float* X  = (const float*)d_in[0];
    const float* Wq = (const float*)d_in[1];
    const float* Wk = (const float*)d_in[2];
    const float* Wv = (const float*)d_in[3];
    float* Out = (float*)d_out;

    char* ws = (char*)d_ws;
    // layout: Wt 768KB @0 ; Qs 2MB @1MB ; Kb 2MB @3MB ; Vt 2MB @5MB ; partials @7MB
    bf16* Wt = (bf16*)(ws);
    bf16* Qs = (bf16*)(ws + (size_t)1 * (1 << 20));
    bf16* Kb = (bf16*)(ws + (size_t)3 * (1 << 20));
    bf16* Vt = (bf16*)(ws + (size_t)5 * (1 << 20));
    size_t base = (size_t)7 << 20;

    // pick split factor deterministically from ws_size
    // need(S) = base + S*4MB (Zp) + 2*S*32KB (Mp,Lp)
    auto need = [](int S) -> size_t {
        return ((size_t)7 << 20) + (size_t)S * ((size_t)NB * NQT * 16 * 128 * 4)
                                 + (size_t)S * 2 * ((size_t)NB * NQT * 16 * 4);
    };
    int S = 1;
    if      (ws_size >= need(8)) S = 8;
    else if (ws_size >= need(4)) S = 4;
    else if (ws_size >= need(2)) S = 2;

    float* Zp = (float*)(ws + base);
    float* Mp = (float*)(ws + base + (size_t)S * NB * NQT * 16 * 128 * 4);
    float* Lp = (float*)(ws + base + (size_t)S * NB * NQT * 16 * 128 * 4
                                   + (size_t)S * NB * NQT * 16 * 4);

    hipLaunchKernelGGL(wt_kernel,   dim3(16, 2, 3), dim3(256), 0, stream, Wq, Wk, Wv, Wt);
    hipLaunchKernelGGL(proj_kernel, dim3(64, 3),    dim3(256), 0, stream, X, Wt, Qs, Kb, Vt);
    hipLaunchKernelGGL(attn_kernel, dim3(S, NQT, NB), dim3(64), 0, stream,
                       Qs, Kb, Vt, Zp, Mp, Lp, Out, S, (S == 1) ? 1 : 0);
    if (S > 1)
        hipLaunchKernelGGL(combine_kernel, dim3(NQT, NB), dim3(256), 0, stream,
                           Zp, Mp, Lp, Out, S);
}